// Round 1
// baseline (2748.115 us; speedup 1.0000x reference)
//
#include <hip/hip_runtime.h>
#include <hip/hip_bf16.h>

// Bidirectional LSTM, B=32 T=512 D=H=512. f32 I/O, bf16 MFMA internally.
//
// R7: latency-restructured persistent kernel, grid=(32,2).
//  - Split MFMA loop: x-part (no h dependence) runs BEFORE the flag poll,
//    inside the post-signal window; h-part runs after h staging.
//  - xA double-buffered in LDS: stage xA(t+1) + issue x(t+2) prefetch at the
//    top of step t (also in the window). 3 barriers/step.
//  - Raw s_barrier + lgkmcnt(0)-only waits where only LDS visibility is
//    needed (keeps x prefetch in flight across barriers); the single full
//    __syncthreads drain sits right before the flag signal, and at that
//    point only the 1 KB h-store is recent.
//  - out-store moved AFTER the signal (off the pre-flag drain).
//  - lengths copied to registers once (no LDS reads for addresses in loop).

typedef __bf16 bf16;
typedef __attribute__((ext_vector_type(8))) __bf16 bf16x8;
typedef __attribute__((ext_vector_type(4))) float f32x4;

__device__ __forceinline__ float sigmoidf_(float x) {
  return 1.f / (1.f + __expf(-x));
}
__device__ __forceinline__ float tanhf_(float x) {
  float e = __expf(-2.f * fabsf(x));
  return copysignf((1.f - e) / (1.f + e), x);
}
__device__ __forceinline__ unsigned ald(const unsigned* p) {
  return __hip_atomic_load(p, __ATOMIC_RELAXED, __HIP_MEMORY_SCOPE_AGENT);
}
__device__ __forceinline__ unsigned long long ald64(const unsigned long long* p) {
  return __hip_atomic_load(p, __ATOMIC_RELAXED, __HIP_MEMORY_SCOPE_AGENT);
}
__device__ __forceinline__ void ast(unsigned* p, unsigned v) {
  __hip_atomic_store(p, v, __ATOMIC_RELAXED, __HIP_MEMORY_SCOPE_AGENT);
}
__device__ __forceinline__ bf16x8 cvt8v(float4 a, float4 b) {
  bf16x8 v;
  v[0] = (bf16)a.x; v[1] = (bf16)a.y; v[2] = (bf16)a.z; v[3] = (bf16)a.w;
  v[4] = (bf16)b.x; v[5] = (bf16)b.y; v[6] = (bf16)b.z; v[7] = (bf16)b.w;
  return v;
}
// Barrier with LDS-visibility only: does NOT drain vmcnt, so in-flight
// global prefetches survive across it.
__device__ __forceinline__ void bar_lgkm() {
  asm volatile("s_waitcnt lgkmcnt(0)\n\ts_barrier" ::: "memory");
}

// ---------------- lengths ----------------
__global__ void lengths_kernel(const int* __restrict__ mask, int* __restrict__ lengths) {
  __shared__ int part[32][8];
  int t = threadIdx.x;
  int b = t >> 3, sub = t & 7;
  int s = 0;
#pragma unroll 8
  for (int k = 0; k < 64; ++k) s += mask[b * 512 + sub + 8 * k];
  part[b][sub] = s;
  __syncthreads();
  if (sub == 0) {
    int tot = 0;
#pragma unroll
    for (int k = 0; k < 8; ++k) tot += part[b][k];
    lengths[b] = tot;
  }
}

// ---------------- fused persistent LSTM ----------------
__global__ __launch_bounds__(256, 1) void lstm_fused(
    const float* __restrict__ x,                                  // [32][512][512] f32
    const float* __restrict__ Wih_f, const float* __restrict__ bih_f,
    const float* __restrict__ Whh_f,
    const float* __restrict__ Wih_b, const float* __restrict__ bih_b,
    const float* __restrict__ Whh_b,
    const int* __restrict__ lengths,
    unsigned* __restrict__ hbuf,        // [2 dir][2 par][32][256] dwords (2 bf16 each)
    unsigned* __restrict__ flags,       // [2][64] dwords; wg s of dir uses flags[dir*64+s]
    float* __restrict__ out) {          // [32][512][1024] f32
  const int s = blockIdx.x;             // h-col slice: cols [16s, 16s+16)
  const int dir = blockIdx.y;
  const float* Wih = dir ? Wih_b : Wih_f;
  const float* Whh = dir ? Whh_b : Whh_f;
  const float* bih = dir ? bih_b : bih_f;
  unsigned* flg = flags + dir * 64;

  const int tid = threadIdx.x;
  const int lane = tid & 63, wave = tid >> 6;
  const int l15 = lane & 15, quad = lane >> 4;

  __shared__ __align__(16) bf16 xA[2][32 * 512];  // 2x32 KB double buffer
  __shared__ __align__(16) bf16 hA[32 * 512];     // 32 KB
  __shared__ float vbuf[4][32][17];
  __shared__ int lenL[32];

  // Weight slices f32 -> bf16 registers (B-frag layout: k=quad*8+j, n=l15).
  bf16x8 wih[16], whh[16];
  {
    int grow = wave * 512 + s * 16 + l15;
#pragma unroll
    for (int k = 0; k < 16; ++k) {
      const float* pw = Wih + (size_t)grow * 512 + k * 32 + quad * 8;
      const float* ph = Whh + (size_t)grow * 512 + k * 32 + quad * 8;
      wih[k] = cvt8v(*(const float4*)pw, *(const float4*)(pw + 4));
      whh[k] = cvt8v(*(const float4*)ph, *(const float4*)(ph + 4));
    }
  }
  const float bv = bih[wave * 512 + s * 16 + l15];
  if (tid < 32) lenL[tid] = lengths[tid];
  __syncthreads();

  const int cb = tid >> 3, cj = (tid & 7) * 2;
  // hoist lengths into registers: per-chunk rotation bases + own-row base
  int lenR[8];
#pragma unroll
  for (int i = 0; i < 8; ++i) lenR[i] = lenL[(i * 256 + tid) >> 6];
  const int lenO = lenL[cb];

  float creg0 = 0.f, creg1 = 0.f;
  unsigned* hb = hbuf + dir * (2 * 32 * 256);

  // Prologue: load x(0), stage xA[0], then issue prefetch of x(1).
  float4 xp[8][2];
#pragma unroll
  for (int i = 0; i < 8; ++i) {
    int c = i * 256 + tid;
    int m = c >> 6, kbp = c & 63;
    int kb = kbp ^ (m & 7);
    int tr = (dir == 0) ? 0 : ((511 + lenR[i]) & 511);
    const float4* p = (const float4*)(x + ((size_t)m * 512 + tr) * 512 + kb * 8);
    xp[i][0] = p[0]; xp[i][1] = p[1];
  }
#pragma unroll
  for (int i = 0; i < 8; ++i) {
    int c = i * 256 + tid;
    *(bf16x8*)(xA[0] + c * 8) = cvt8v(xp[i][0], xp[i][1]);
  }
#pragma unroll
  for (int i = 0; i < 8; ++i) {
    int c = i * 256 + tid;
    int m = c >> 6, kbp = c & 63;
    int kb = kbp ^ (m & 7);
    int tr = (dir == 0) ? 1 : ((510 + lenR[i]) & 511);
    const float4* p = (const float4*)(x + ((size_t)m * 512 + tr) * 512 + kb * 8);
    xp[i][0] = p[0]; xp[i][1] = p[1];
  }
  bar_lgkm();  // xA[0] staged

  for (int step = 0; step < 512; ++step) {
    const int par = step & 1;
    const unsigned* hprev = hb + par * (32 * 256);
    unsigned* hnext = hb + (par ^ 1) * (32 * 256);
    const bf16* xcur = xA[par];
    bf16* xnxt = xA[par ^ 1];

    // ---- post-signal window work (no dependence on incoming h) ----
    // stage xA(step+1) from landed xp regs (other buffer: no barrier needed;
    // visibility to other waves is guaranteed by this step's C/E barriers)
    if (step < 511) {
#pragma unroll
      for (int i = 0; i < 8; ++i) {
        int c = i * 256 + tid;
        *(bf16x8*)(xnxt + c * 8) = cvt8v(xp[i][0], xp[i][1]);
      }
    }
    // issue x(step+2) prefetch EARLY so the vmcnt FIFO drains it before the
    // post-poll h loads need servicing
    if (step < 510) {
#pragma unroll
      for (int i = 0; i < 8; ++i) {
        int c = i * 256 + tid;
        int m = c >> 6, kbp = c & 63;
        int kb = kbp ^ (m & 7);
        int tr = (dir == 0) ? (step + 2) : ((509 - step + lenR[i]) & 511);
        const float4* p = (const float4*)(x + ((size_t)m * 512 + tr) * 512 + kb * 8);
        xp[i][0] = p[0]; xp[i][1] = p[1];
      }
    }

    // x-part MFMAs: v += x@Wih^T (+bias) — overlaps producers' flag latency
    f32x4 acc0 = {bv, bv, bv, bv};
    f32x4 acc1 = {bv, bv, bv, bv};
#pragma unroll
    for (int k = 0; k < 16; ++k) {
      int kb = k * 4 + quad;
      int sw = (kb ^ (l15 & 7)) * 8;
      bf16x8 ax0 = *(const bf16x8*)(xcur + l15 * 512 + sw);
      bf16x8 ax1 = *(const bf16x8*)(xcur + (16 + l15) * 512 + sw);
      acc0 = __builtin_amdgcn_mfma_f32_16x16x32_bf16(ax0, wih[k], acc0, 0, 0, 0);
      acc1 = __builtin_amdgcn_mfma_f32_16x16x32_bf16(ax1, wih[k], acc1, 0, 0, 0);
    }
    __builtin_amdgcn_sched_barrier(0);  // pin window work before the poll

    // ---- wait for h(step) ----
    if (step > 0) {
      unsigned target = (unsigned)step;
      bool done;
      do {
        unsigned v = (lane < 32) ? ald(flg + lane) : target;
        done = __all((int)(v >= target));
        if (!done) __builtin_amdgcn_s_sleep(1);
      } while (!done);
    }

    // stage h (8B coherent loads) -> swizzled LDS
#pragma unroll
    for (int i = 0; i < 8; ++i) {
      int c = i * 256 + tid;
      int m = c >> 6, kbp = c & 63;
      int kb = kbp ^ (m & 7);
      const unsigned long long* hp =
          (const unsigned long long*)(hprev + m * 256 + kb * 4);
      unsigned long long d0 = ald64(hp), d1 = ald64(hp + 1);
      *(unsigned long long*)(hA + c * 8) = d0;
      *(unsigned long long*)(hA + c * 8 + 4) = d1;
    }
    bar_lgkm();  // C: hA (and xnxt) visible; x prefetch stays in flight

    // h-part MFMAs: v += h@Whh^T
#pragma unroll
    for (int k = 0; k < 16; ++k) {
      int kb = k * 4 + quad;
      int sw = (kb ^ (l15 & 7)) * 8;
      bf16x8 ah0 = *(const bf16x8*)(hA + l15 * 512 + sw);
      bf16x8 ah1 = *(const bf16x8*)(hA + (16 + l15) * 512 + sw);
      acc0 = __builtin_amdgcn_mfma_f32_16x16x32_bf16(ah0, whh[k], acc0, 0, 0, 0);
      acc1 = __builtin_amdgcn_mfma_f32_16x16x32_bf16(ah1, whh[k], acc1, 0, 0, 0);
    }
#pragma unroll
    for (int r = 0; r < 4; ++r) {
      vbuf[wave][quad * 4 + r][l15] = acc0[r];
      vbuf[wave][16 + quad * 4 + r][l15] = acc1[r];
    }
    bar_lgkm();  // D: vbuf ready

    // cell update
    float i0 = vbuf[0][cb][cj],     f0 = vbuf[1][cb][cj];
    float g0 = vbuf[2][cb][cj],     o0 = vbuf[3][cb][cj];
    float i1 = vbuf[0][cb][cj + 1], f1 = vbuf[1][cb][cj + 1];
    float g1 = vbuf[2][cb][cj + 1], o1 = vbuf[3][cb][cj + 1];
    float c0 = sigmoidf_(f0) * creg0 + sigmoidf_(i0) * tanhf_(g0);
    float c1 = sigmoidf_(f1) * creg1 + sigmoidf_(i1) * tanhf_(g1);
    creg0 = c0; creg1 = c1;
    float h0 = tanhf_(c0) * sigmoidf_(o0);
    float h1 = tanhf_(c1) * sigmoidf_(o1);
    unsigned ulo = (unsigned)__builtin_bit_cast(unsigned short, (bf16)h0);
    unsigned uhi = (unsigned)__builtin_bit_cast(unsigned short, (bf16)h1);
    ast(hnext + cb * 256 + s * 8 + (tid & 7), ulo | (uhi << 16));

    // E: the ONLY full drain; at this point the only recent vmem op is the
    // 1 KB h-store (out-store of step-1 and x prefetch landed long ago).
    __syncthreads();
    if (tid == 0 && step < 511) ast(flg + s, (unsigned)(step + 1));

    // out-store AFTER the signal (nobody consumes it)
    int tr = (dir == 0) ? step : ((511 - step + lenO) & 511);
    *(float2*)(out + (size_t)(cb * 512 + tr) * 1024 + dir * 512 + s * 16 + cj) =
        make_float2(h0, h1);
  }
}

extern "C" void kernel_launch(void* const* d_in, const int* in_sizes, int n_in,
                              void* d_out, int out_size, void* d_ws, size_t ws_size,
                              hipStream_t stream) {
  (void)in_sizes; (void)n_in; (void)out_size; (void)ws_size;
  const float* x    = (const float*)d_in[0];
  const int*   mask = (const int*)  d_in[1];
  const float* Wihf = (const float*)d_in[2];
  const float* bihf = (const float*)d_in[3];
  const float* Whhf = (const float*)d_in[4];
  const float* Wihb = (const float*)d_in[5];
  const float* bihb = (const float*)d_in[6];
  const float* Whhb = (const float*)d_in[7];
  float* out = (float*)d_out;

  char* ws = (char*)d_ws;
  unsigned* flags = (unsigned*)ws;            // [2][64] dwords = 512 B
  int* lengths = (int*)(ws + 512);            // 128 B
  unsigned* hbuf = (unsigned*)(ws + 1024);    // 131072 B
  const size_t head = 1024 + (size_t)2 * 2 * 32 * 256 * sizeof(unsigned);

  hipMemsetAsync(d_ws, 0, head, stream);      // re-arm flags + h0 = c0 = 0 every call
  lengths_kernel<<<1, 256, 0, stream>>>(mask, lengths);
  lstm_fused<<<dim3(32, 2), 256, 0, stream>>>(
      x, Wihf, bihf, Whhf, Wihb, bihb, Whhb, lengths, hbuf, flags, out);
}